// Round 2
// baseline (114.835 us; speedup 1.0000x reference)
//
#include <hip/hip_runtime.h>
#include <math.h>

#define BATCH 512
#define HW 12544            // 112*112
#define PARTS 4             // blocks per sample
#define VECS (HW / 4)       // 3136 float4 per plane
#define VEC_PER_PART (VECS / PARTS)  // 784
#define NBLK (BATCH * PARTS)         // 2048 blocks = 32 waves/CU at 256 thr

// Fused kernel: per-block partial sums of squared diffs -> ws; last arriving
// block performs the scalar finalize and writes the single-loss output.
// Deterministic: partials land in fixed slots; finalize reads them in fixed
// order; counter is memset to 0 by the host-side launch each call.
__global__ __launch_bounds__(256) void combine_loss_fused(
        const float* __restrict__ preds1,
        const float* __restrict__ cams1,
        const float* __restrict__ preds1_back,
        const float* __restrict__ preds2,
        const float* __restrict__ cams2,
        const int* __restrict__ y,
        const int* __restrict__ d_index,
        float* __restrict__ ws,              // NBLK*2 partial floats
        unsigned int* __restrict__ counter,  // 1 uint, zeroed per call
        float* __restrict__ out) {
    const int blk = blockIdx.x;
    const int b = blk >> 2;      // PARTS == 4
    const int p = blk & 3;
    const int tid = threadIdx.x;
    const int idx = d_index[0] & 1;

    // channel-1 plane of sample b
    const size_t cur_off = ((size_t)(idx * BATCH + b) * 2 + 1) * (size_t)HW;
    const size_t oth_off = ((size_t)((1 - idx) * BATCH + b) * 2 + 1) * (size_t)HW;

    const float4* __restrict__ c1 = (const float4*)(cams1 + cur_off);
    const float4* __restrict__ c2 = (const float4*)(cams2 + cur_off);
    const float4* __restrict__ tg = (const float4*)(cams1 + oth_off);

    float s_er = 0.f, s_sd = 0.f;
    const int start = p * VEC_PER_PART;
    const int end = start + VEC_PER_PART;
    for (int i = start + tid; i < end; i += 256) {
        float4 a = c1[i];
        float4 c = c2[i];
        float4 t = tg[i];
        float d0 = a.x - c.x, d1 = a.y - c.y, d2 = a.z - c.z, d3 = a.w - c.w;
        s_er += d0 * d0 + d1 * d1 + d2 * d2 + d3 * d3;
        float e0 = a.x - t.x, e1 = a.y - t.y, e2 = a.z - t.z, e3 = a.w - t.w;
        s_sd += e0 * e0 + e1 * e1 + e2 * e2 + e3 * e3;
    }

    // wave (64-lane) reduce, then cross-wave via LDS
    for (int o = 32; o > 0; o >>= 1) {
        s_er += __shfl_down(s_er, o);
        s_sd += __shfl_down(s_sd, o);
    }
    __shared__ float r_er[4];
    __shared__ float r_sd[4];
    __shared__ unsigned int s_last;
    const int wid = tid >> 6;
    const int lane = tid & 63;
    if (lane == 0) { r_er[wid] = s_er; r_sd[wid] = s_sd; }
    __syncthreads();
    if (tid == 0) {
        float e = r_er[0] + r_er[1] + r_er[2] + r_er[3];
        float s = r_sd[0] + r_sd[1] + r_sd[2] + r_sd[3];
        ws[(size_t)blk * 2 + 0] = e;
        ws[(size_t)blk * 2 + 1] = s;
        __threadfence();  // release partials to device scope (cross-XCD)
        unsigned int old = __hip_atomic_fetch_add(
            counter, 1u, __ATOMIC_ACQ_REL, __HIP_MEMORY_SCOPE_AGENT);
        s_last = (old == (unsigned int)(NBLK - 1)) ? 1u : 0u;
    }
    __syncthreads();
    if (s_last == 0u) return;

    // ---- last block: finalize ----
    __threadfence();  // acquire: make all remote partials visible

    float loss_acc = 0.f, sd_acc = 0.f;
    for (int bb = tid; bb < BATCH; bb += 256) {
        float er_sum = 0.f, sd_sum = 0.f;
        for (int q = 0; q < PARTS; ++q) {
            er_sum += ws[(size_t)(bb * PARTS + q) * 2 + 0];
            sd_sum += ws[(size_t)(bb * PARTS + q) * 2 + 1];
        }

        const float p1a = preds1[(size_t)(idx * BATCH + bb) * 2 + 0];
        const float p1b = preds1[(size_t)(idx * BATCH + bb) * 2 + 1];
        const float poa = preds1[(size_t)((1 - idx) * BATCH + bb) * 2 + 0];
        const float pob = preds1[(size_t)((1 - idx) * BATCH + bb) * 2 + 1];
        const float p2a = preds2[(size_t)(idx * BATCH + bb) * 2 + 0];
        const float p2b = preds2[(size_t)(idx * BATCH + bb) * 2 + 1];
        const float pba = preds1_back[(size_t)(idx * BATCH + bb) * 2 + 0];
        const float pbb = preds1_back[(size_t)(idx * BATCH + bb) * 2 + 1];
        const int yi = y[bb];
        const float yf = (float)yi;

        // 2-class logsumexp
        float m1 = fmaxf(p1a, p1b);
        float lse1 = m1 + logf(expf(p1a - m1) + expf(p1b - m1));
        float m2 = fmaxf(p2a, p2b);
        float lse2 = m2 + logf(expf(p2a - m2) + expf(p2b - m2));
        float mb = fmaxf(pba, pbb);
        float lseb = mb + logf(expf(pba - mb) + expf(pbb - mb));

        const float ce1 = lse1 - (yi == 1 ? p1b : p1a);
        const float ce2 = lse2 - (yi == 1 ? p2b : p2a);
        const float ce = 0.5f * (ce1 + ce2);

        const float er = yf * (er_sum / (float)HW);
        const float ce_back = 0.5f * (lseb - pba) * yf;

        const float prob1 = expf(p1b - lse1);
        const int cur_pred = (p1b > p1a) ? 1 : 0;
        const int flag_pred = (pob > poa) ? 1 : 0;

        const bool cond = (cur_pred != flag_pred) && (cur_pred == 0) && (yi == 1);
        const float w = cond ? prob1 : 1.0f;
        loss_acc += w * (ce + er + ce_back);

        const float same = (cur_pred == flag_pred) ? yf : 0.f;
        sd_acc += sd_sum * same;
    }

    for (int o = 32; o > 0; o >>= 1) {
        loss_acc += __shfl_down(loss_acc, o);
        sd_acc += __shfl_down(sd_acc, o);
    }
    __shared__ float f_l[4];
    __shared__ float f_s[4];
    if (lane == 0) { f_l[wid] = loss_acc; f_s[wid] = sd_acc; }
    __syncthreads();
    if (tid == 0) {
        float ls = f_l[0] + f_l[1] + f_l[2] + f_l[3];
        float ss = f_s[0] + f_s[1] + f_s[2] + f_s[3];
        out[0] = ls / (float)BATCH + ss / ((float)BATCH * (float)HW);
    }
}

extern "C" void kernel_launch(void* const* d_in, const int* in_sizes, int n_in,
                              void* d_out, int out_size, void* d_ws, size_t ws_size,
                              hipStream_t stream) {
    const float* preds1      = (const float*)d_in[0];
    const float* cams1       = (const float*)d_in[1];
    const float* preds1_back = (const float*)d_in[2];
    const float* preds2      = (const float*)d_in[3];
    const float* cams2       = (const float*)d_in[4];
    const int*   y           = (const int*)d_in[5];
    const int*   d_index     = (const int*)d_in[6];
    float* out = (float*)d_out;
    float* ws = (float*)d_ws;
    // counter lives past the partials (NBLK*2*4 = 16 KB), 64 B aligned
    unsigned int* counter = (unsigned int*)((char*)d_ws + 16384);

    hipMemsetAsync(counter, 0, sizeof(unsigned int), stream);
    combine_loss_fused<<<NBLK, 256, 0, stream>>>(
        preds1, cams1, preds1_back, preds2, cams2, y, d_index, ws, counter, out);
}

// Round 3
// 19.376 us; speedup vs baseline: 5.9267x; 5.9267x over previous
//
#include <hip/hip_runtime.h>
#include <math.h>

#define BATCH 512
#define HW 12544            // 112*112
#define PARTS 4             // blocks per sample
#define VECS (HW / 4)       // 3136 float4 per plane
#define VEC_PER_PART (VECS / PARTS)  // 784
#define NBLK (BATCH * PARTS)         // 2048 blocks

// ws layout (floats):
//   [0 .. NBLK*2)           per-block partials {er, sd}
//   [NBLK*2 .. NBLK*2+B*3)  per-sample scalars {A, B, C}
#define WS_SCALARS (NBLK * 2)

// Kernel 1: stream the three HW planes, write per-block partial sums.
// p==0 blocks also compute the per-sample scalar terms (hidden under streaming).
__global__ __launch_bounds__(256) void combine_loss_partials(
        const float* __restrict__ preds1,
        const float* __restrict__ cams1,
        const float* __restrict__ preds1_back,
        const float* __restrict__ preds2,
        const float* __restrict__ cams2,
        const int* __restrict__ y,
        const int* __restrict__ d_index,
        float* __restrict__ ws) {
    const int blk = blockIdx.x;
    const int b = blk >> 2;      // PARTS == 4
    const int p = blk & 3;
    const int tid = threadIdx.x;
    const int idx = d_index[0] & 1;

    // channel-1 plane of sample b
    const size_t cur_off = ((size_t)(idx * BATCH + b) * 2 + 1) * (size_t)HW;
    const size_t oth_off = ((size_t)((1 - idx) * BATCH + b) * 2 + 1) * (size_t)HW;

    const float4* __restrict__ c1 = (const float4*)(cams1 + cur_off);
    const float4* __restrict__ c2 = (const float4*)(cams2 + cur_off);
    const float4* __restrict__ tg = (const float4*)(cams1 + oth_off);

    // per-sample scalar math on one lane of p==0 blocks (overlaps streaming)
    if (p == 0 && tid == 255) {
        const float p1a = preds1[(size_t)(idx * BATCH + b) * 2 + 0];
        const float p1b = preds1[(size_t)(idx * BATCH + b) * 2 + 1];
        const float poa = preds1[(size_t)((1 - idx) * BATCH + b) * 2 + 0];
        const float pob = preds1[(size_t)((1 - idx) * BATCH + b) * 2 + 1];
        const float p2a = preds2[(size_t)(idx * BATCH + b) * 2 + 0];
        const float p2b = preds2[(size_t)(idx * BATCH + b) * 2 + 1];
        const float pba = preds1_back[(size_t)(idx * BATCH + b) * 2 + 0];
        const float pbb = preds1_back[(size_t)(idx * BATCH + b) * 2 + 1];
        const int yi = y[b];
        const float yf = (float)yi;

        float m1 = fmaxf(p1a, p1b);
        float lse1 = m1 + logf(expf(p1a - m1) + expf(p1b - m1));
        float m2 = fmaxf(p2a, p2b);
        float lse2 = m2 + logf(expf(p2a - m2) + expf(p2b - m2));
        float mb = fmaxf(pba, pbb);
        float lseb = mb + logf(expf(pba - mb) + expf(pbb - mb));

        const float ce1 = lse1 - (yi == 1 ? p1b : p1a);
        const float ce2 = lse2 - (yi == 1 ? p2b : p2a);
        const float ce = 0.5f * (ce1 + ce2);
        const float ce_back = 0.5f * (lseb - pba) * yf;

        const float prob1 = expf(p1b - lse1);
        const int cur_pred = (p1b > p1a) ? 1 : 0;
        const int flag_pred = (pob > poa) ? 1 : 0;
        const bool cond = (cur_pred != flag_pred) && (cur_pred == 0) && (yi == 1);
        const float w = cond ? prob1 : 1.0f;
        const float same = (cur_pred == flag_pred) ? yf : 0.f;

        ws[WS_SCALARS + b * 3 + 0] = w * (ce + ce_back);     // A
        ws[WS_SCALARS + b * 3 + 1] = w * yf / (float)HW;     // B (er factor)
        ws[WS_SCALARS + b * 3 + 2] = same;                   // C (sd factor)
    }

    float s_er = 0.f, s_sd = 0.f;
    const int start = p * VEC_PER_PART;
    const int end = start + VEC_PER_PART;
    for (int i = start + tid; i < end; i += 256) {
        float4 a = c1[i];
        float4 c = c2[i];
        float4 t = tg[i];
        float d0 = a.x - c.x, d1 = a.y - c.y, d2 = a.z - c.z, d3 = a.w - c.w;
        s_er += d0 * d0 + d1 * d1 + d2 * d2 + d3 * d3;
        float e0 = a.x - t.x, e1 = a.y - t.y, e2 = a.z - t.z, e3 = a.w - t.w;
        s_sd += e0 * e0 + e1 * e1 + e2 * e2 + e3 * e3;
    }

    for (int o = 32; o > 0; o >>= 1) {
        s_er += __shfl_down(s_er, o);
        s_sd += __shfl_down(s_sd, o);
    }
    __shared__ float r_er[4];
    __shared__ float r_sd[4];
    const int wid = tid >> 6;
    const int lane = tid & 63;
    if (lane == 0) { r_er[wid] = s_er; r_sd[wid] = s_sd; }
    __syncthreads();
    if (tid == 0) {
        ws[(size_t)blk * 2 + 0] = r_er[0] + r_er[1] + r_er[2] + r_er[3];
        ws[(size_t)blk * 2 + 1] = r_sd[0] + r_sd[1] + r_sd[2] + r_sd[3];
    }
}

// Kernel 2: pure gather + FMA + reduce. One block, 512 threads.
__global__ __launch_bounds__(512) void combine_loss_finalize(
        const float* __restrict__ ws,
        float* __restrict__ out) {
    const int b = threadIdx.x;  // sample id

    float er_sum = 0.f, sd_sum = 0.f;
    #pragma unroll
    for (int q = 0; q < PARTS; ++q) {
        er_sum += ws[(size_t)(b * PARTS + q) * 2 + 0];
        sd_sum += ws[(size_t)(b * PARTS + q) * 2 + 1];
    }
    const float A = ws[WS_SCALARS + b * 3 + 0];
    const float B = ws[WS_SCALARS + b * 3 + 1];
    const float C = ws[WS_SCALARS + b * 3 + 2];

    float loss_b = A + B * er_sum;
    float sd_b = C * sd_sum;

    for (int o = 32; o > 0; o >>= 1) {
        loss_b += __shfl_down(loss_b, o);
        sd_b += __shfl_down(sd_b, o);
    }
    __shared__ float r_l[8];
    __shared__ float r_s[8];
    const int wid = b >> 6;
    const int lane = b & 63;
    if (lane == 0) { r_l[wid] = loss_b; r_s[wid] = sd_b; }
    __syncthreads();
    if (b == 0) {
        float ls = 0.f, ss = 0.f;
        #pragma unroll
        for (int wv = 0; wv < 8; ++wv) { ls += r_l[wv]; ss += r_s[wv]; }
        out[0] = ls / (float)BATCH + ss / ((float)BATCH * (float)HW);
    }
}

extern "C" void kernel_launch(void* const* d_in, const int* in_sizes, int n_in,
                              void* d_out, int out_size, void* d_ws, size_t ws_size,
                              hipStream_t stream) {
    const float* preds1      = (const float*)d_in[0];
    const float* cams1       = (const float*)d_in[1];
    const float* preds1_back = (const float*)d_in[2];
    const float* preds2      = (const float*)d_in[3];
    const float* cams2       = (const float*)d_in[4];
    const int*   y           = (const int*)d_in[5];
    const int*   d_index     = (const int*)d_in[6];
    float* out = (float*)d_out;
    float* ws = (float*)d_ws;

    combine_loss_partials<<<NBLK, 256, 0, stream>>>(
        preds1, cams1, preds1_back, preds2, cams2, y, d_index, ws);
    combine_loss_finalize<<<1, 512, 0, stream>>>(ws, out);
}